// Round 9
// baseline (775.906 us; speedup 1.0000x reference)
//
#include <hip/hip_runtime.h>

#define CONT_F 13
#define CATE_F 26
#define FF 39
#define DD 40
#define NCOMB 741
#define BB 2048
#define SUB0 40
#define SUB1 5
#define HH 100
#define K0 1560            // FF*DD rows of XT (e-part)
#define KTOT 5265          // K0 + NCOMB*SUB1 rows of XT
#define NPART 15           // fc0 K-splits: 15 x 352 = 5280 >= 5265
#define KSPL 352           // 11 chunks of 32 per split
#define CPX 93             // combs per XCD (93*8 = 744, 3 dummies)

using short8 = __attribute__((ext_vector_type(8))) short;   // 8 bf16 (4 VGPRs)
using f32x4  = __attribute__((ext_vector_type(4))) float;   // MFMA acc

// f32 -> bf16 RNE (finite values only)
__device__ __forceinline__ short f2bf(float f) {
    unsigned u = __float_as_uint(f);
    unsigned r = (u + 0x7FFFu + ((u >> 16) & 1u)) >> 16;
    return (short)r;
}
__device__ __forceinline__ float bf2f(short h) {
    return __uint_as_float(((unsigned)(unsigned short)h) << 16);
}

// ---------------------------------------------------------------- build e -> XT rows [0,1560)
__global__ __launch_bounds__(256) void build_eT_kernel(
    const float* __restrict__ conts, const int* __restrict__ cates,
    const float* __restrict__ emb, float* __restrict__ XT)
{
    const int f = blockIdx.x;
    const int b = blockIdx.y * 256 + threadIdx.x;
    float* xo = XT + (size_t)(f * DD) * BB + b;
    if (f < CONT_F) {
        const float cv = conts[b * CONT_F + f];
        const float* em = emb + f * DD;
        #pragma unroll
        for (int d = 0; d < DD; ++d)
            xo[(size_t)d * BB] = em[d] * cv;
    } else {
        const int tok = cates[b * CATE_F + (f - CONT_F)];
        const float4* er = (const float4*)(emb + (size_t)tok * DD);
        #pragma unroll
        for (int d4 = 0; d4 < DD / 4; ++d4) {
            const float4 v = er[d4];
            xo[(size_t)(d4 * 4 + 0) * BB] = v.x;
            xo[(size_t)(d4 * 4 + 1) * BB] = v.y;
            xo[(size_t)(d4 * 4 + 2) * BB] = v.z;
            xo[(size_t)(d4 * 4 + 3) * BB] = v.w;
        }
    }
}

// ---------------------------------------------------------------- subnet via split-bf16 MFMA
// R8 kernel + XCD-aware comb partitioning (R2-proven): XCD k owns combs
// [93k,93k+93); halves adjacent -> weights L2-resident (1.8MB/XCD), e L3-hot.
__global__ __launch_bounds__(256, 2) void subnet_mfma_kernel(
    const float* __restrict__ XT, const float* __restrict__ w0,
    const float* __restrict__ b0, const float* __restrict__ sln0w,
    const float* __restrict__ sln0b, const float* __restrict__ w1,
    const float* __restrict__ b1, const float* __restrict__ sln1w,
    const float* __restrict__ sln1b, float* __restrict__ XTz)
{
    const int wgid   = blockIdx.x;
    const int xcd    = wgid & 7;
    const int within = wgid >> 3;       // 0..185: comb-major, halves adjacent
    const int c_loc  = within >> 1;
    const int half   = within & 1;
    const int c      = xcd * CPX + c_loc;
    if (c >= NCOMB) return;
    const int t    = threadIdx.x;
    const int w    = t >> 6;            // wave 0..3
    const int l    = t & 63;
    const int l15  = l & 15;
    const int grp  = l >> 4;            // 0..3

    // unrank c -> (r,s)
    int r = 0, rem = c;
    while (rem >= FF - 1 - r) { rem -= FF - 1 - r; ++r; }
    const int s = r + 1 + rem;
    const float* XTr = XT + (size_t)(r * DD) * BB;
    const float* XTs = XT + (size_t)(s * DD) * BB;

    // ---- prologue: A-frags (W^T hi/lo), o = mt*16+l15, k = ks*32+grp*8+j
    short8 Ah[3][4], Al[3][4];
    #pragma unroll
    for (int mt = 0; mt < 3; ++mt) {
        const int o = mt * 16 + l15;
        #pragma unroll
        for (int ks = 0; ks < 4; ++ks) {
            short8 hh, ll;
            #pragma unroll
            for (int j = 0; j < 8; ++j) {
                const int k = ks * 32 + grp * 8 + j;
                const float v = (o < SUB0 && k < 120)
                    ? w0[(size_t)c * 4800 + k * SUB0 + o] : 0.f;
                const short h = f2bf(v);
                hh[j] = h;
                ll[j] = f2bf(v - bf2f(h));
            }
            Ah[mt][ks] = hh;
            Al[mt][ks] = ll;
        }
    }

    // ---- prologue: epilogue constants (C row o = mt*16 + grp*4 + rg)
    float b0r[3][4], slwr[3][4], slbr[3][4], w1r[3][4][5];
    #pragma unroll
    for (int mt = 0; mt < 3; ++mt) {
        #pragma unroll
        for (int rg = 0; rg < 4; ++rg) {
            const int o = mt * 16 + grp * 4 + rg;
            const bool re = (o < SUB0);
            b0r[mt][rg]  = re ? b0[c * SUB0 + o]   : 0.f;
            slwr[mt][rg] = re ? sln0w[o]           : 0.f;
            slbr[mt][rg] = re ? sln0b[o]           : 0.f;
            #pragma unroll
            for (int j = 0; j < 5; ++j)
                w1r[mt][rg][j] = re ? w1[(size_t)c * 200 + o * 5 + j] : 0.f;
        }
    }
    float b1r[5], s1w[5], s1b[5];
    #pragma unroll
    for (int j = 0; j < 5; ++j) {
        b1r[j] = b1[c * SUB1 + j];
        s1w[j] = sln1w[j];
        s1b[j] = sln1b[j];
    }

    // ---- main loop: 16 iters x 64 batch cols ----
    for (int it = half * 16; it < half * 16 + 16; ++it) {
        const int bb = it * 64 + w * 16 + l15;

        f32x4 acc0 = {0.f, 0.f, 0.f, 0.f};
        f32x4 acc1 = {0.f, 0.f, 0.f, 0.f};
        f32x4 acc2 = {0.f, 0.f, 0.f, 0.f};

        #pragma unroll
        for (int ks = 0; ks < 4; ++ks) {
            short8 Bh, Bl;
            #pragma unroll
            for (int j = 0; j < 8; ++j) {
                const int k = ks * 32 + grp * 8 + j;
                float v;
                if (ks == 0) {
                    v = XTr[(size_t)k * BB + bb];
                } else {
                    const int kp = (k < 40) ? k : ((k >= 80) ? k - 80 : 0);
                    const int kq = (k >= 40) ? ((k < 80) ? k - 40 : k - 80) : 0;
                    const float vp = XTr[(size_t)kp * BB + bb];
                    const float vq = XTs[(size_t)kq * BB + bb];
                    v = (k < 40) ? vp : ((k < 80) ? vq : vp * vq);
                    if (k >= 120) v = 0.f;
                }
                const short h = f2bf(v);
                Bh[j] = h;
                Bl[j] = f2bf(v - bf2f(h));
            }
            acc0 = __builtin_amdgcn_mfma_f32_16x16x32_bf16(Ah[0][ks], Bh, acc0, 0, 0, 0);
            acc1 = __builtin_amdgcn_mfma_f32_16x16x32_bf16(Ah[1][ks], Bh, acc1, 0, 0, 0);
            acc2 = __builtin_amdgcn_mfma_f32_16x16x32_bf16(Ah[2][ks], Bh, acc2, 0, 0, 0);
            acc0 = __builtin_amdgcn_mfma_f32_16x16x32_bf16(Ah[0][ks], Bl, acc0, 0, 0, 0);
            acc1 = __builtin_amdgcn_mfma_f32_16x16x32_bf16(Ah[1][ks], Bl, acc1, 0, 0, 0);
            acc2 = __builtin_amdgcn_mfma_f32_16x16x32_bf16(Ah[2][ks], Bl, acc2, 0, 0, 0);
            acc0 = __builtin_amdgcn_mfma_f32_16x16x32_bf16(Al[0][ks], Bh, acc0, 0, 0, 0);
            acc1 = __builtin_amdgcn_mfma_f32_16x16x32_bf16(Al[1][ks], Bh, acc1, 0, 0, 0);
            acc2 = __builtin_amdgcn_mfma_f32_16x16x32_bf16(Al[2][ks], Bh, acc2, 0, 0, 0);
        }

        // ---- epilogue: bias + LN40 + relu + (40->5) + LN5 + relu + store ----
        float vv[3][4];
        #pragma unroll
        for (int rg = 0; rg < 4; ++rg) {
            vv[0][rg] = acc0[rg] + b0r[0][rg];
            vv[1][rg] = acc1[rg] + b0r[1][rg];
            vv[2][rg] = acc2[rg] + b0r[2][rg];
        }
        float sum = 0.f, sq = 0.f;
        #pragma unroll
        for (int mt = 0; mt < 3; ++mt)
            #pragma unroll
            for (int rg = 0; rg < 4; ++rg) {
                const float x = vv[mt][rg];
                sum += x;
                sq = fmaf(x, x, sq);
            }
        sum += __shfl_xor(sum, 16); sum += __shfl_xor(sum, 32);
        sq  += __shfl_xor(sq, 16);  sq  += __shfl_xor(sq, 32);
        const float mean = sum * 0.025f;
        const float var  = sq * 0.025f - mean * mean;
        const float inv  = rsqrtf(var + 1e-5f);

        float p[5] = {0.f, 0.f, 0.f, 0.f, 0.f};
        #pragma unroll
        for (int mt = 0; mt < 3; ++mt)
            #pragma unroll
            for (int rg = 0; rg < 4; ++rg) {
                const float hx = fmaxf(
                    fmaf((vv[mt][rg] - mean) * inv, slwr[mt][rg], slbr[mt][rg]), 0.f);
                #pragma unroll
                for (int j = 0; j < 5; ++j)
                    p[j] = fmaf(w1r[mt][rg][j], hx, p[j]);
            }
        #pragma unroll
        for (int j = 0; j < 5; ++j) {
            p[j] += __shfl_xor(p[j], 16);
            p[j] += __shfl_xor(p[j], 32);
        }
        float a2[5];
        float sum2 = 0.f, sq2 = 0.f;
        #pragma unroll
        for (int j = 0; j < 5; ++j) {
            a2[j] = p[j] + b1r[j];
            sum2 += a2[j];
            sq2 = fmaf(a2[j], a2[j], sq2);
        }
        const float m2   = sum2 * 0.2f;
        const float var2 = sq2 * 0.2f - m2 * m2;
        const float inv2 = rsqrtf(var2 + 1e-5f);

        if (grp == 0) {
            float* zo = XTz + (size_t)(K0 + c * SUB1) * BB + bb;
            #pragma unroll
            for (int j = 0; j < 5; ++j) {
                const float z = fmaf((a2[j] - m2) * inv2, s1w[j], s1b[j]);
                zo[(size_t)j * BB] = z > 0.f ? z : 0.f;
            }
        }
    }
}

// ---------------------------------------------------------------- fc0 via split-bf16 MFMA
// C^T[o=100pad112][b] = fc0w^T @ XT. Block = (64-col tile, K-split of 352).
// B-frags straight from k-major XT (lane l15 = col, coalesced); A-frags from
// fc0w rows (16 consecutive floats per quarter-wave line). Writes partial[split].
__global__ __launch_bounds__(256, 2) void fc0_mfma_kernel(
    const float* __restrict__ XT, const float* __restrict__ fc0w,
    float* __restrict__ partial)
{
    const int ct    = blockIdx.x;       // 0..31
    const int split = blockIdx.y;       // 0..14
    const int t    = threadIdx.x;
    const int w    = t >> 6;
    const int l    = t & 63;
    const int l15  = l & 15;
    const int grp  = l >> 4;
    const int col  = ct * 64 + w * 16 + l15;

    f32x4 acc[7];
    #pragma unroll
    for (int mt = 0; mt < 7; ++mt) acc[mt] = (f32x4){0.f, 0.f, 0.f, 0.f};

    for (int ch = 0; ch < 11; ++ch) {   // 11 x 32 = 352 k per split
        const int kbase = split * KSPL + ch * 32;

        short8 Bh, Bl;
        #pragma unroll
        for (int j = 0; j < 8; ++j) {
            const int kk = kbase + grp * 8 + j;
            const float v = (kk < KTOT) ? XT[(size_t)kk * BB + col] : 0.f;
            const short h = f2bf(v);
            Bh[j] = h;
            Bl[j] = f2bf(v - bf2f(h));
        }
        #pragma unroll
        for (int mt = 0; mt < 7; ++mt) {
            const int o = mt * 16 + l15;
            short8 Ahh, All;
            #pragma unroll
            for (int j = 0; j < 8; ++j) {
                const int kk = kbase + grp * 8 + j;
                const float v = (o < HH && kk < KTOT)
                    ? fc0w[(size_t)kk * HH + o] : 0.f;
                const short h = f2bf(v);
                Ahh[j] = h;
                All[j] = f2bf(v - bf2f(h));
            }
            acc[mt] = __builtin_amdgcn_mfma_f32_16x16x32_bf16(Ahh, Bh, acc[mt], 0, 0, 0);
            acc[mt] = __builtin_amdgcn_mfma_f32_16x16x32_bf16(Ahh, Bl, acc[mt], 0, 0, 0);
            acc[mt] = __builtin_amdgcn_mfma_f32_16x16x32_bf16(All, Bh, acc[mt], 0, 0, 0);
        }
    }

    // D layout: col = l15-lane col, row o = mt*16 + grp*4 + rg
    float* po = partial + ((size_t)split * BB + col) * HH;
    #pragma unroll
    for (int mt = 0; mt < 7; ++mt)
        #pragma unroll
        for (int rg = 0; rg < 4; ++rg) {
            const int o = mt * 16 + grp * 4 + rg;
            if (o < HH) po[o] = acc[mt][rg];
        }
}

// ---------------------------------------------------------------- fused fc0-reduce + LN + relu + fc1 + LN + out + sigmoid
__global__ __launch_bounds__(256) void fc0rh_kernel(
    const float* __restrict__ partial, const float* __restrict__ fc0b,
    const float* __restrict__ ln0w, const float* __restrict__ ln0b,
    const float* __restrict__ fc1w, const float* __restrict__ fc1b,
    const float* __restrict__ ln1w, const float* __restrict__ ln1b,
    const float* __restrict__ outw, const float* __restrict__ outb,
    float* __restrict__ out)
{
    __shared__ float xs[4][104];
    const int wl   = threadIdx.x >> 6;
    const int lane = threadIdx.x & 63;
    const int row  = blockIdx.x * 4 + wl;

    float s0 = fc0b[lane];
    float s1 = (lane < 36) ? fc0b[64 + lane] : 0.f;
    #pragma unroll
    for (int p = 0; p < NPART; ++p) {
        const float* pr = partial + ((size_t)p * BB + row) * HH;
        s0 += pr[lane];
        if (lane < 36) s1 += pr[64 + lane];
    }
    float sum = s0 + ((lane < 36) ? s1 : 0.f);
    #pragma unroll
    for (int off = 32; off; off >>= 1) sum += __shfl_xor(sum, off, 64);
    float m  = sum * 0.01f;
    float d0 = s0 - m;
    float d1 = (lane < 36) ? (s1 - m) : 0.f;
    float vs = d0 * d0 + d1 * d1;
    #pragma unroll
    for (int off = 32; off; off >>= 1) vs += __shfl_xor(vs, off, 64);
    float inv = rsqrtf(vs * 0.01f + 1e-5f);
    {
        float x0 = d0 * inv * ln0w[lane] + ln0b[lane];
        xs[wl][lane] = x0 > 0.f ? x0 : 0.f;
        if (lane < 36) {
            float x1 = d1 * inv * ln0w[64 + lane] + ln0b[64 + lane];
            xs[wl][64 + lane] = x1 > 0.f ? x1 : 0.f;
        }
    }

    float a0 = fc1b[lane];
    float a1 = (lane < 36) ? fc1b[64 + lane] : 0.f;
    for (int k = 0; k < HH; ++k) {
        const float xv = xs[wl][k];
        a0 = fmaf(fc1w[k * HH + lane], xv, a0);
        if (lane < 36) a1 = fmaf(fc1w[k * HH + 64 + lane], xv, a1);
    }
    sum = a0 + ((lane < 36) ? a1 : 0.f);
    #pragma unroll
    for (int off = 32; off; off >>= 1) sum += __shfl_xor(sum, off, 64);
    m  = sum * 0.01f;
    d0 = a0 - m;
    d1 = (lane < 36) ? (a1 - m) : 0.f;
    vs = d0 * d0 + d1 * d1;
    #pragma unroll
    for (int off = 32; off; off >>= 1) vs += __shfl_xor(vs, off, 64);
    inv = rsqrtf(vs * 0.01f + 1e-5f);

    float x0 = d0 * inv * ln1w[lane] + ln1b[lane];
    x0 = x0 > 0.f ? x0 : 0.f;
    float t = x0 * outw[lane];
    if (lane < 36) {
        float x1 = d1 * inv * ln1w[64 + lane] + ln1b[64 + lane];
        x1 = x1 > 0.f ? x1 : 0.f;
        t = fmaf(x1, outw[64 + lane], t);
    }
    #pragma unroll
    for (int off = 32; off; off >>= 1) t += __shfl_xor(t, off, 64);
    if (lane == 0) {
        const float z = t + outb[0];
        out[row] = 1.f / (1.f + expf(-z));
    }
}

// ---------------------------------------------------------------- launch
extern "C" void kernel_launch(void* const* d_in, const int* in_sizes, int n_in,
                              void* d_out, int out_size, void* d_ws, size_t ws_size,
                              hipStream_t stream)
{
    const float* conts = (const float*)d_in[0];
    const int*   cates = (const int*)d_in[1];
    const float* emb   = (const float*)d_in[3];
    const float* w0    = (const float*)d_in[4];
    const float* b0    = (const float*)d_in[5];
    const float* sln0w = (const float*)d_in[6];
    const float* sln0b = (const float*)d_in[7];
    const float* w1    = (const float*)d_in[8];
    const float* b1    = (const float*)d_in[9];
    const float* sln1w = (const float*)d_in[10];
    const float* sln1b = (const float*)d_in[11];
    const float* fc0w  = (const float*)d_in[12];
    const float* fc0b  = (const float*)d_in[13];
    const float* ln0w  = (const float*)d_in[14];
    const float* ln0b  = (const float*)d_in[15];
    const float* fc1w  = (const float*)d_in[16];
    const float* fc1b  = (const float*)d_in[17];
    const float* ln1w  = (const float*)d_in[18];
    const float* ln1b  = (const float*)d_in[19];
    const float* outw  = (const float*)d_in[20];
    const float* outb  = (const float*)d_in[21];
    float* out = (float*)d_out;

    // ws: XT (5265x2048 f32 = 43.1MB) | partial (15x2048x100 = 12.3MB)
    float* XT      = (float*)d_ws;
    float* partial = XT + (size_t)KTOT * BB;

    build_eT_kernel<<<dim3(FF, BB / 256), 256, 0, stream>>>(conts, cates, emb, XT);
    subnet_mfma_kernel<<<8 * CPX * 2, 256, 0, stream>>>(
        XT, w0, b0, sln0w, sln0b, w1, b1, sln1w, sln1b, XT);
    fc0_mfma_kernel<<<dim3(BB / 64, NPART), 256, 0, stream>>>(XT, fc0w, partial);
    fc0rh_kernel<<<BB / 4, 256, 0, stream>>>(
        partial, fc0b, ln0w, ln0b, fc1w, fc1b, ln1w, ln1b, outw, outb, out);
}